// Round 1
// baseline (292.678 us; speedup 1.0000x reference)
//
#include <hip/hip_runtime.h>

// Problem constants (from reference)
#define N1C 50000
#define NNC 16
#define NIC 64
#define NDC 128
#define KC  128   // 2*NI
#define QB  8     // queries per block
#define MR  128   // QB*NN rows per block
#define LDX 136   // padded LDS row stride (bf16 elems): 272B -> bank stride 4, 2-way (free)

typedef __bf16 bf16x8 __attribute__((ext_vector_type(8)));
typedef float f32x4 __attribute__((ext_vector_type(4)));
typedef unsigned short us8v __attribute__((ext_vector_type(8)));

static __device__ __forceinline__ unsigned short f2bf(float f) {
    unsigned int u = __builtin_bit_cast(unsigned int, f);
    u += 0x7fffu + ((u >> 16) & 1u);   // round-to-nearest-even
    return (unsigned short)(u >> 16);
}

static __device__ __forceinline__ float elu(float x) {
    return x > 0.f ? x : __expf(x) - 1.f;
}

__global__ __launch_bounds__(256, 2)
void fused_knn_mlp(const float* __restrict__ features1,
                   const float* __restrict__ features2,
                   const float* __restrict__ x1,
                   const float* __restrict__ x2,
                   const int*   __restrict__ topk,
                   const float* __restrict__ W1,
                   const float* __restrict__ b1,
                   const float* __restrict__ W2,
                   const float* __restrict__ b2,
                   const float* __restrict__ radius,
                   float* __restrict__ out)
{
    __shared__ unsigned short sX[MR * LDX];   // A tile / h1 tile (bf16)
    __shared__ unsigned short sW[NDC * LDX];  // W^T tile (bf16), [d][k]
    __shared__ float sWgt[MR];
    __shared__ int   sIdx[MR];
    __shared__ float sB1[NDC];
    __shared__ float sB2[NDC];

    const int tid  = threadIdx.x;
    const int blk  = blockIdx.x;
    const int lane = tid & 63;
    const int wave = tid >> 6;
    const int quad = lane >> 4;
    const int l16  = lane & 15;

    // ---- phase 0: neighbor indices, distance weights, biases ----
    if (tid < MR) {
        const int q   = tid >> 4;
        const int nq  = blk * QB + q;
        const int idx = topk[nq * NNC + (tid & 15)];
        sIdx[tid] = idx;
        const float r = radius[0];
        const float inv2r2 = 1.f / (2.f * r * r);
        const float dx = x2[idx * 3 + 0] - x1[nq * 3 + 0];
        const float dy = x2[idx * 3 + 1] - x1[nq * 3 + 1];
        const float dz = x2[idx * 3 + 2] - x1[nq * 3 + 2];
        const float w = __expf(-(dx * dx + dy * dy + dz * dz) * inv2r2);
        sWgt[tid] = (idx == 0) ? 0.f : w;
    } else {
        const int d = tid - 128;
        sB1[d] = b1[d];
        sB2[d] = b2[d];
    }
    __syncthreads();

    // ---- stage A tile: row r = [features2[idx_r] (64) | features1[nq] (64)], bf16 ----
    #pragma unroll
    for (int j = 0; j < 16; ++j) {
        const int e = j * 256 + tid;
        const int r = e >> 5;       // row 0..127
        const int c = e & 31;       // float4 index 0..31 within the 128-wide row
        const float* src;
        int colX;
        if (c < 16) {
            src  = features2 + (size_t)sIdx[r] * NIC + c * 4;
            colX = c * 4;
        } else {
            const int nq = blk * QB + (r >> 4);
            src  = features1 + (size_t)nq * NIC + (c - 16) * 4;
            colX = 64 + (c - 16) * 4;
        }
        const float4 v = *(const float4*)src;
        ushort4 pv;
        pv.x = f2bf(v.x); pv.y = f2bf(v.y); pv.z = f2bf(v.z); pv.w = f2bf(v.w);
        *(ushort4*)&sX[r * LDX + colX] = pv;
    }

    // ---- stage W1 transposed: sW[d][i] = W1[i][d] (coalesced column reads) ----
    {
        const int d  = tid & 127;
        const int i0 = (tid >> 7) * 64;
        #pragma unroll
        for (int ii = 0; ii < 64; ii += 8) {
            us8v v;
            #pragma unroll
            for (int u = 0; u < 8; ++u)
                v[u] = f2bf(W1[(size_t)(i0 + ii + u) * NDC + d]);
            *(us8v*)&sW[d * LDX + i0 + ii] = v;
        }
    }
    __syncthreads();

    // ---- layer 1: acc = A @ W1  (wave owns rows [32*wave, 32*wave+32), all 128 cols) ----
    f32x4 acc[2][8];
    #pragma unroll
    for (int mt = 0; mt < 2; ++mt)
        #pragma unroll
        for (int nt = 0; nt < 8; ++nt)
            acc[mt][nt] = (f32x4){0.f, 0.f, 0.f, 0.f};

    #pragma unroll
    for (int ks = 0; ks < 4; ++ks) {
        const int k0 = ks * 32 + quad * 8;
        const bf16x8 a0 = *(const bf16x8*)&sX[(wave * 32 + l16) * LDX + k0];
        const bf16x8 a1 = *(const bf16x8*)&sX[(wave * 32 + 16 + l16) * LDX + k0];
        #pragma unroll
        for (int nt = 0; nt < 8; ++nt) {
            const bf16x8 b = *(const bf16x8*)&sW[(nt * 16 + l16) * LDX + k0];
            acc[0][nt] = __builtin_amdgcn_mfma_f32_16x16x32_bf16(a0, b, acc[0][nt], 0, 0, 0);
            acc[1][nt] = __builtin_amdgcn_mfma_f32_16x16x32_bf16(a1, b, acc[1][nt], 0, 0, 0);
        }
    }

    // ---- h1 = elu(acc + b1) -> sX (each wave writes only its own 32 rows) ----
    // C/D layout: col = nt*16 + l16, row = 16*tile + quad*4 + reg  [m89/m91]
    #pragma unroll
    for (int mt = 0; mt < 2; ++mt) {
        const int q = wave * 2 + mt;
        #pragma unroll
        for (int nt = 0; nt < 8; ++nt) {
            const int col = nt * 16 + l16;
            const float bb = sB1[col];
            #pragma unroll
            for (int reg = 0; reg < 4; ++reg) {
                const int row = q * 16 + quad * 4 + reg;
                sX[row * LDX + col] = f2bf(elu(acc[mt][nt][reg] + bb));
            }
        }
    }
    __syncthreads();   // all waves done reading sW(W1); h1 visible

    // ---- restage W2 ----
    {
        const int d  = tid & 127;
        const int i0 = (tid >> 7) * 64;
        #pragma unroll
        for (int ii = 0; ii < 64; ii += 8) {
            us8v v;
            #pragma unroll
            for (int u = 0; u < 8; ++u)
                v[u] = f2bf(W2[(size_t)(i0 + ii + u) * NDC + d]);
            *(us8v*)&sW[d * LDX + i0 + ii] = v;
        }
    }
    #pragma unroll
    for (int mt = 0; mt < 2; ++mt)
        #pragma unroll
        for (int nt = 0; nt < 8; ++nt)
            acc[mt][nt] = (f32x4){0.f, 0.f, 0.f, 0.f};
    __syncthreads();

    // ---- layer 2: acc = h1 @ W2 ----
    #pragma unroll
    for (int ks = 0; ks < 4; ++ks) {
        const int k0 = ks * 32 + quad * 8;
        const bf16x8 a0 = *(const bf16x8*)&sX[(wave * 32 + l16) * LDX + k0];
        const bf16x8 a1 = *(const bf16x8*)&sX[(wave * 32 + 16 + l16) * LDX + k0];
        #pragma unroll
        for (int nt = 0; nt < 8; ++nt) {
            const bf16x8 b = *(const bf16x8*)&sW[(nt * 16 + l16) * LDX + k0];
            acc[0][nt] = __builtin_amdgcn_mfma_f32_16x16x32_bf16(a0, b, acc[0][nt], 0, 0, 0);
            acc[1][nt] = __builtin_amdgcn_mfma_f32_16x16x32_bf16(a1, b, acc[1][nt], 0, 0, 0);
        }
    }

    // ---- epilogue: out[q][d] = sum_k w[k] * elu(h2[k][d]) ----
    // Each 16x16 C-tile is exactly one query's 16 neighbors: reduce 4 regs + xor-shuffle quads.
    #pragma unroll
    for (int mt = 0; mt < 2; ++mt) {
        const int q = wave * 2 + mt;
        const float4 wv = *(const float4*)&sWgt[q * 16 + quad * 4];
        #pragma unroll
        for (int nt = 0; nt < 8; ++nt) {
            const int col = nt * 16 + l16;
            const float bb = sB2[col];
            float s = elu(acc[mt][nt][0] + bb) * wv.x
                    + elu(acc[mt][nt][1] + bb) * wv.y
                    + elu(acc[mt][nt][2] + bb) * wv.z
                    + elu(acc[mt][nt][3] + bb) * wv.w;
            s += __shfl_xor(s, 16, 64);
            s += __shfl_xor(s, 32, 64);
            if (lane < 16) {
                out[(size_t)(blk * QB + q) * NDC + col] = s;
            }
        }
    }
}

extern "C" void kernel_launch(void* const* d_in, const int* in_sizes, int n_in,
                              void* d_out, int out_size, void* d_ws, size_t ws_size,
                              hipStream_t stream) {
    const float* features1 = (const float*)d_in[0];
    const float* features2 = (const float*)d_in[1];
    const float* x1        = (const float*)d_in[2];
    const float* x2        = (const float*)d_in[3];
    // d_in[4], d_in[5] = nuv1, nuv2 (unused by reference)
    const int*   topk      = (const int*)d_in[6];
    const float* W1        = (const float*)d_in[7];
    const float* b1        = (const float*)d_in[8];
    const float* W2        = (const float*)d_in[9];
    const float* b2        = (const float*)d_in[10];
    const float* radius    = (const float*)d_in[11];
    float* out = (float*)d_out;

    dim3 grid(N1C / QB);   // 50000 / 8 = 6250, exact
    fused_knn_mlp<<<grid, 256, 0, stream>>>(features1, features2, x1, x2, topk,
                                            W1, b1, W2, b2, radius, out);
}

// Round 2
// 258.568 us; speedup vs baseline: 1.1319x; 1.1319x over previous
//
#include <hip/hip_runtime.h>

// Problem constants (from reference)
#define N1C 50000
#define NNC 16
#define NIC 64
#define NDC 128
#define QB  8     // queries per block
#define MR  128   // QB*NN rows per block
#define LDX 136   // padded LDS row stride (bf16 elems): 272B -> dword stride 68 (bank stride 4)
#define WSH 18432 // padded W image: 2304 chunks of 8 shorts = 9 * 256 exactly (uniform copy loop)

typedef __bf16 bf16x8 __attribute__((ext_vector_type(8)));
typedef float f32x4 __attribute__((ext_vector_type(4)));

#if defined(__has_builtin)
#if __has_builtin(__builtin_amdgcn_cvt_pk_bf16_f32)
#define HAVE_PK_BF16 1
#endif
#endif

#ifdef HAVE_PK_BF16
typedef __bf16 bf16x2 __attribute__((ext_vector_type(2)));
static __device__ __forceinline__ unsigned int pkbf(float a, float b) {
    bf16x2 r = __builtin_amdgcn_cvt_pk_bf16_f32(a, b);
    return __builtin_bit_cast(unsigned int, r);
}
#else
static __device__ __forceinline__ unsigned short f2bf_sw(float f) {
    unsigned int u = __builtin_bit_cast(unsigned int, f);
    u += 0x7fffu + ((u >> 16) & 1u);
    return (unsigned short)(u >> 16);
}
static __device__ __forceinline__ unsigned int pkbf(float a, float b) {
    return (unsigned int)f2bf_sw(a) | ((unsigned int)f2bf_sw(b) << 16);
}
#endif

static __device__ __forceinline__ unsigned short bf1(float a) {
    return (unsigned short)pkbf(a, 0.f);
}

static __device__ __forceinline__ float elu(float x) {
    return x > 0.f ? x : __expf(x) - 1.f;
}

// ---- prep: W^T (bf16, padded stride LDX) images into ws. Runs once per launch (~1.5us). ----
__global__ void prep_w(const float* __restrict__ W1, const float* __restrict__ W2,
                       unsigned short* __restrict__ wsW) {
    const int idx = blockIdx.x * 256 + threadIdx.x;   // 0 .. 2*WSH-1
    const int m   = idx >= WSH;
    const int o   = idx - m * WSH;
    const int d   = o / LDX;          // 0..135
    const int kk  = o - d * LDX;      // 0..135
    const float* W = m ? W2 : W1;
    float v = (d < NDC && kk < NDC) ? W[(size_t)kk * NDC + d] : 0.f;
    wsW[idx] = bf1(v);
}

__global__ __launch_bounds__(256, 2)
void fused_knn_mlp(const float* __restrict__ features1,
                   const float* __restrict__ features2,
                   const float* __restrict__ x1,
                   const float* __restrict__ x2,
                   const int*   __restrict__ topk,
                   const float* __restrict__ b1,
                   const float* __restrict__ b2,
                   const float* __restrict__ radius,
                   const unsigned short* __restrict__ wsW,
                   float* __restrict__ out)
{
    __shared__ unsigned short sX[MR * LDX];   // A tile / h1 tile (bf16)
    __shared__ unsigned short sW[WSH];        // W^T tile (bf16), [d][k], stride LDX
    __shared__ float sWgt[MR];
    __shared__ int   sIdx[MR];
    __shared__ float sB1[NDC];
    __shared__ float sB2[NDC];

    const int tid  = threadIdx.x;
    const int blk  = blockIdx.x;
    const int lane = tid & 63;
    const int wave = tid >> 6;
    const int quad = lane >> 4;
    const int l16  = lane & 15;

    // ---- prefetch W2 image into registers (global latency overlaps phase0+staging+layer1) ----
    uint4 w2r[9];
    {
        const uint4* w2p = (const uint4*)(wsW + WSH);
        #pragma unroll
        for (int it = 0; it < 9; ++it)
            w2r[it] = w2p[it * 256 + tid];
    }

    // ---- phase 0: neighbor indices, distance weights, biases ----
    if (tid < MR) {
        const int q   = tid >> 4;
        const int nq  = blk * QB + q;
        const int idx = topk[nq * NNC + (tid & 15)];
        sIdx[tid] = idx;
        const float r = radius[0];
        const float inv2r2 = 1.f / (2.f * r * r);
        const float dx = x2[idx * 3 + 0] - x1[nq * 3 + 0];
        const float dy = x2[idx * 3 + 1] - x1[nq * 3 + 1];
        const float dz = x2[idx * 3 + 2] - x1[nq * 3 + 2];
        const float w = __expf(-(dx * dx + dy * dy + dz * dz) * inv2r2);
        sWgt[tid] = (idx == 0) ? 0.f : w;
    } else {
        const int d = tid - 128;
        sB1[d] = b1[d];
        sB2[d] = b2[d];
    }
    __syncthreads();

    // ---- stage A tile rows: [features2[idx_r] (64) | features1[nq] (64)], bf16 ----
    // features2 part: 128 rows x 16 float4-chunks, all lanes active
    #pragma unroll
    for (int jj = 0; jj < 8; ++jj) {
        const int chunk = jj * 256 + tid;  // 0..2047
        const int r = chunk >> 4;
        const int c = chunk & 15;
        const float4 v = *(const float4*)(features2 + (size_t)sIdx[r] * NIC + c * 4);
        uint2 p;
        p.x = pkbf(v.x, v.y);
        p.y = pkbf(v.z, v.w);
        *(uint2*)&sX[r * LDX + c * 4] = p;
    }
    // features1 part: 8 queries x 16 chunks, broadcast to 16 rows (8 rows per half)
    {
        const int q = tid >> 5;            // 0..7
        const int c = tid & 15;
        const int h = (tid >> 4) & 1;      // row half
        const float4 v = *(const float4*)(features1 + (size_t)(blk * QB + q) * NIC + c * 4);
        uint2 p;
        p.x = pkbf(v.x, v.y);
        p.y = pkbf(v.z, v.w);
        #pragma unroll
        for (int rr = 0; rr < 8; ++rr)
            *(uint2*)&sX[(q * 16 + h * 8 + rr) * LDX + NIC + c * 4] = p;
    }
    // W1 image: flat copy, 9 uniform iterations
    {
        const uint4* w1p = (const uint4*)wsW;
        #pragma unroll
        for (int it = 0; it < 9; ++it)
            *(uint4*)&sW[(it * 256 + tid) * 8] = w1p[it * 256 + tid];
    }
    __syncthreads();

    // ---- layer 1: acc = A @ W1 + b1 (bias folded into acc init) ----
    f32x4 acc[2][8];
    #pragma unroll
    for (int nt = 0; nt < 8; ++nt) {
        const float bb = sB1[nt * 16 + l16];
        acc[0][nt] = (f32x4){bb, bb, bb, bb};
        acc[1][nt] = acc[0][nt];
    }

    #pragma unroll
    for (int ks = 0; ks < 4; ++ks) {
        const int k0 = ks * 32 + quad * 8;
        const bf16x8 a0 = *(const bf16x8*)&sX[(wave * 32 + l16) * LDX + k0];
        const bf16x8 a1 = *(const bf16x8*)&sX[(wave * 32 + 16 + l16) * LDX + k0];
        #pragma unroll
        for (int nt = 0; nt < 8; ++nt) {
            const bf16x8 b = *(const bf16x8*)&sW[(nt * 16 + l16) * LDX + k0];
            acc[0][nt] = __builtin_amdgcn_mfma_f32_16x16x32_bf16(a0, b, acc[0][nt], 0, 0, 0);
            acc[1][nt] = __builtin_amdgcn_mfma_f32_16x16x32_bf16(a1, b, acc[1][nt], 0, 0, 0);
        }
    }

    // ---- h1 = elu(acc) -> sX (each wave writes/reads only its own 32 rows; no barrier needed) ----
    // C/D layout: col = nt*16 + l16, row = 16*tile + quad*4 + reg  [m89/m91]
    #pragma unroll
    for (int mt = 0; mt < 2; ++mt) {
        const int q = wave * 2 + mt;
        #pragma unroll
        for (int nt = 0; nt < 8; ++nt) {
            const int col = nt * 16 + l16;
            #pragma unroll
            for (int reg = 0; reg < 4; ++reg) {
                const int row = q * 16 + quad * 4 + reg;
                sX[row * LDX + col] = bf1(elu(acc[mt][nt][reg]));
            }
        }
    }
    __syncthreads();   // all waves done reading sW(W1)

    // ---- restage W2 from registers (no global latency here) ----
    #pragma unroll
    for (int it = 0; it < 9; ++it)
        *(uint4*)&sW[(it * 256 + tid) * 8] = w2r[it];

    #pragma unroll
    for (int nt = 0; nt < 8; ++nt) {
        const float bb = sB2[nt * 16 + l16];
        acc[0][nt] = (f32x4){bb, bb, bb, bb};
        acc[1][nt] = acc[0][nt];
    }
    __syncthreads();

    // ---- layer 2: acc = h1 @ W2 + b2 ----
    #pragma unroll
    for (int ks = 0; ks < 4; ++ks) {
        const int k0 = ks * 32 + quad * 8;
        const bf16x8 a0 = *(const bf16x8*)&sX[(wave * 32 + l16) * LDX + k0];
        const bf16x8 a1 = *(const bf16x8*)&sX[(wave * 32 + 16 + l16) * LDX + k0];
        #pragma unroll
        for (int nt = 0; nt < 8; ++nt) {
            const bf16x8 b = *(const bf16x8*)&sW[(nt * 16 + l16) * LDX + k0];
            acc[0][nt] = __builtin_amdgcn_mfma_f32_16x16x32_bf16(a0, b, acc[0][nt], 0, 0, 0);
            acc[1][nt] = __builtin_amdgcn_mfma_f32_16x16x32_bf16(a1, b, acc[1][nt], 0, 0, 0);
        }
    }

    // ---- epilogue: out[q][d] = sum_k w[k] * elu(h2[k][d]) ----
    #pragma unroll
    for (int mt = 0; mt < 2; ++mt) {
        const int q = wave * 2 + mt;
        const float4 wv = *(const float4*)&sWgt[q * 16 + quad * 4];
        #pragma unroll
        for (int nt = 0; nt < 8; ++nt) {
            const int col = nt * 16 + l16;
            float s = elu(acc[mt][nt][0]) * wv.x
                    + elu(acc[mt][nt][1]) * wv.y
                    + elu(acc[mt][nt][2]) * wv.z
                    + elu(acc[mt][nt][3]) * wv.w;
            s += __shfl_xor(s, 16, 64);
            s += __shfl_xor(s, 32, 64);
            if (lane < 16) {
                out[(size_t)(blk * QB + q) * NDC + col] = s;
            }
        }
    }
}

extern "C" void kernel_launch(void* const* d_in, const int* in_sizes, int n_in,
                              void* d_out, int out_size, void* d_ws, size_t ws_size,
                              hipStream_t stream) {
    const float* features1 = (const float*)d_in[0];
    const float* features2 = (const float*)d_in[1];
    const float* x1        = (const float*)d_in[2];
    const float* x2        = (const float*)d_in[3];
    // d_in[4], d_in[5] = nuv1, nuv2 (unused by reference)
    const int*   topk      = (const int*)d_in[6];
    const float* W1        = (const float*)d_in[7];
    const float* b1        = (const float*)d_in[8];
    const float* W2        = (const float*)d_in[9];
    const float* b2        = (const float*)d_in[10];
    const float* radius    = (const float*)d_in[11];
    float* out = (float*)d_out;
    unsigned short* wsW = (unsigned short*)d_ws;   // 2*WSH shorts = 72 KB

    prep_w<<<dim3(2 * WSH / 256), 256, 0, stream>>>(W1, W2, wsW);
    fused_knn_mlp<<<dim3(N1C / QB), 256, 0, stream>>>(features1, features2, x1, x2, topk,
                                                      b1, b2, radius, wsW, out);
}